// Round 4
// baseline (79.262 us; speedup 1.0000x reference)
//
#include <hip/hip_runtime.h>
#include <hip/hip_bf16.h>

// ShapeletLearner: B=2048, Q=1024, K=32, L=64, S=993
// dist[b,s,l] = wsq[b,s] - (2/K)*cross[b,s,l] + ssq[l];  out = min_s(dist) @ fcw^T + fcb
// cross via bf16 MFMA. c2k=2^-4 pre-folded into A (exact); -wsq folded into MFMA C operand.
// R4: __launch_bounds__(256,4) -> 4 blocks/CU resident (latency hiding); unroll 8.

#define B_   2048
#define Q_   1024
#define K_   32
#define L_   64
#define S_   993
#define SP   1024          // padded S (64 tiles of 16)
#define CL   1064          // per-copy length
#define LTSN 1064          // fp32 ts pad length

using frag_ab = __attribute__((ext_vector_type(8))) short;   // 8 bf16
using f32x4   = __attribute__((ext_vector_type(4))) float;

__global__ __launch_bounds__(256, 4)
void shapelet_mfma(const float* __restrict__ ts,
                   const float* __restrict__ shp,
                   const float* __restrict__ fcw,
                   const float* __restrict__ fcb,
                   float* __restrict__ out)
{
    __shared__ __align__(16) float           lts[LTSN];      // fp32 ts row (zero-padded)
    __shared__ __align__(16) __hip_bfloat16  tsb[8][CL];     // 8 shift-copies: tsb[c][j] = ts[c+j]
    __shared__ __align__(16) float           wsq[SP];        // 1e30 for s >= 993
    __shared__ float                         ssq[L_];
    __shared__ float                         red[4][L_];

    const int tid  = threadIdx.x;
    const int b    = blockIdx.x;
    const int lane = tid & 63;
    const int w    = tid >> 6;
    const int n    = lane & 15;      // MFMA col (s within tile) / A row (l within tile)
    const int q    = lane >> 4;      // MFMA quad

    // ---- prefetch FC params early (used only in epilogue; hides load latency) ----
    float fw0 = 0.f, fw1 = 0.f, fb0 = 0.f, fb1 = 0.f;
    if (tid < L_) {
        fw0 = fcw[tid];
        fw1 = fcw[L_ + tid];
        fb0 = fcb[0];
        fb1 = fcb[1];
    }

    // ---- stage ts row (1 float4/thread) + zero pad ----
    {
        const float4* g  = (const float4*)(ts + (size_t)b * Q_);
        float4*       l4 = (float4*)lts;
        l4[tid] = g[tid];
        if (tid < (LTSN - Q_) / 4)
            l4[Q_ / 4 + tid] = make_float4(0.f, 0.f, 0.f, 0.f);
    }
    // ---- ssq (exact fp32) ----
    if (tid < L_) {
        const float* sp = shp + tid * K_;
        float s = 0.f;
        #pragma unroll
        for (int k = 0; k < K_; ++k) s = fmaf(sp[k], sp[k], s);
        ssq[tid] = s * (1.0f / K_);
    }
    // ---- A fragments: shapelets * 2^-4 (exact bf16 scale), built once ----
    // A[m=lane&15][k=q*8+j]
    frag_ab afrag[4];
    #pragma unroll
    for (int f = 0; f < 4; ++f) {
        const float4* sp = (const float4*)(shp + (f * 16 + n) * K_ + q * 8);
        float4 x0 = sp[0], x1 = sp[1];
        union { frag_ab v; __hip_bfloat162 p[4]; } u;
        u.p[0] = __float22bfloat162_rn(make_float2(x0.x * 0.0625f, x0.y * 0.0625f));
        u.p[1] = __float22bfloat162_rn(make_float2(x0.z * 0.0625f, x0.w * 0.0625f));
        u.p[2] = __float22bfloat162_rn(make_float2(x1.x * 0.0625f, x1.y * 0.0625f));
        u.p[3] = __float22bfloat162_rn(make_float2(x1.z * 0.0625f, x1.w * 0.0625f));
        afrag[f] = u.v;
    }
    __syncthreads();

    // ---- build 8 bf16 shift-copies: read 10 floats once, emit 8 packed pairs ----
    for (int j = 2 * tid; j < 1048; j += 512) {
        float v[10];
        const float2* p2 = (const float2*)(lts + j);     // j even -> 8B aligned
        #pragma unroll
        for (int i = 0; i < 5; ++i) { float2 x = p2[i]; v[2*i] = x.x; v[2*i+1] = x.y; }
        #pragma unroll
        for (int c = 0; c < 8; ++c)
            *(__hip_bfloat162*)&tsb[c][j] = __float22bfloat162_rn(make_float2(v[c], v[c+1]));
    }
    // ---- wsq: 4 consecutive s per thread, sliding sum, exact fp32 ----
    {
        const int s0 = 4 * tid;
        float v[36];
        const float4* p = (const float4*)(lts + s0);
        #pragma unroll
        for (int t = 0; t < 9; ++t) {
            float4 x = p[t];
            v[4*t+0] = x.x; v[4*t+1] = x.y; v[4*t+2] = x.z; v[4*t+3] = x.w;
        }
        float sq = 0.f;
        #pragma unroll
        for (int k = 0; k < K_; ++k) sq = fmaf(v[k], v[k], sq);
        float o0 = (s0 + 0 < S_) ? sq * (1.0f / K_) : 1e30f;
        sq = sq + v[32] * v[32] - v[0] * v[0];
        float o1 = (s0 + 1 < S_) ? sq * (1.0f / K_) : 1e30f;
        sq = sq + v[33] * v[33] - v[1] * v[1];
        float o2 = (s0 + 2 < S_) ? sq * (1.0f / K_) : 1e30f;
        sq = sq + v[34] * v[34] - v[2] * v[2];
        float o3 = (s0 + 3 < S_) ? sq * (1.0f / K_) : 1e30f;
        *(float4*)&wsq[s0] = make_float4(o0, o1, o2, o3);
    }
    __syncthreads();

    // ---- main loop: wave w -> s-tiles [w*16, w*16+16) ----
    // D = (2/K)*cross - wsq  (scale in A, -wsq in C operand); maximize D.
    const __hip_bfloat16* bsrc = &tsb[n & 7][8 * q + (n & 8)];
    float rm[4][4];
    #pragma unroll
    for (int f = 0; f < 4; ++f)
        #pragma unroll
        for (int r = 0; r < 4; ++r) rm[f][r] = -3e38f;

    #pragma unroll 8
    for (int t = w * 16; t < w * 16 + 16; ++t) {
        const int s_base = t * 16;
        frag_ab bv = *(const frag_ab*)(bsrc + s_base);
        const float nw = -wsq[s_base + n];
        f32x4 cin = {nw, nw, nw, nw};
        #pragma unroll
        for (int f = 0; f < 4; ++f) {
            f32x4 d = __builtin_amdgcn_mfma_f32_16x16x32_bf16(afrag[f], bv, cin, 0, 0, 0);
            #pragma unroll
            for (int r = 0; r < 4; ++r)
                rm[f][r] = fmaxf(rm[f][r], d[r]);
        }
    }

    // ---- reduce max across the 16 cols (lanes within quad group) ----
    #pragma unroll
    for (int f = 0; f < 4; ++f)
        #pragma unroll
        for (int r = 0; r < 4; ++r) {
            float v = rm[f][r];
            v = fmaxf(v, __shfl_xor(v, 1, 64));
            v = fmaxf(v, __shfl_xor(v, 2, 64));
            v = fmaxf(v, __shfl_xor(v, 4, 64));
            v = fmaxf(v, __shfl_xor(v, 8, 64));
            rm[f][r] = v;
        }
    if (n == 0) {
        #pragma unroll
        for (int f = 0; f < 4; ++f)
            #pragma unroll
            for (int r = 0; r < 4; ++r)
                red[w][f * 16 + q * 4 + r] = rm[f][r];
    }
    __syncthreads();

    // ---- final: combine waves, dist = ssq - ymax, FC, wave-64 reduce ----
    if (tid < L_) {
        const int l = tid;
        float y = fmaxf(fmaxf(red[0][l], red[1][l]), fmaxf(red[2][l], red[3][l]));
        float d = ssq[l] - y;
        float p0 = d * fw0;
        float p1 = d * fw1;
        #pragma unroll
        for (int off = 32; off > 0; off >>= 1) {
            p0 += __shfl_down(p0, off, 64);
            p1 += __shfl_down(p1, off, 64);
        }
        if (l == 0) {
            out[(size_t)b * 2 + 0] = p0 + fb0;
            out[(size_t)b * 2 + 1] = p1 + fb1;
        }
    }
}

extern "C" void kernel_launch(void* const* d_in, const int* in_sizes, int n_in,
                              void* d_out, int out_size, void* d_ws, size_t ws_size,
                              hipStream_t stream) {
    const float* ts  = (const float*)d_in[0];   // (B, Q) fp32
    const float* shp = (const float*)d_in[1];   // (L, K) fp32
    const float* fcw = (const float*)d_in[2];   // (2, L) fp32
    const float* fcb = (const float*)d_in[3];   // (2,)  fp32
    float* o = (float*)d_out;                   // (B, 2) fp32

    shapelet_mfma<<<B_, 256, 0, stream>>>(ts, shp, fcw, fcb, o);
}

// Round 6
// 78.315 us; speedup vs baseline: 1.0121x; 1.0121x over previous
//
#include <hip/hip_runtime.h>
#include <hip/hip_bf16.h>

// ShapeletLearner: B=2048, Q=1024, K=32, L=64, S=993
// dist[b,s,l] = wsq[b,s] - (2/K)*cross[b,s,l] + ssq[l];  out = min_s(dist) @ fcw^T + fcb
// cross via bf16 MFMA; c2k=2^-4 folded into A (exact); -wsq in MFMA C operand.
// R6 = R5 with the bit_cast compile fix: LDS-pipe diet — global-direct copy build,
// single-wave wsq, transposed wsqT preload, DPP (VALU-pipe) max-scan epilogue.

#define B_   2048
#define Q_   1024
#define K_   32
#define L_   64
#define S_   993
#define CL   1048          // per-copy length (max pos 1040+8)
#define WROW 20            // wsqT padded row (16 + 4): b128-aligned, conflict-light

using frag_ab = __attribute__((ext_vector_type(8))) short;   // 8 bf16
using f32x4   = __attribute__((ext_vector_type(4))) float;

static __device__ __forceinline__ unsigned pack_bf16x2(float a, float b) {
    union { __hip_bfloat162 h; unsigned u; } cv;
    cv.h = __float22bfloat162_rn(make_float2(a, b));
    return cv.u;
}

// DPP row_shr max-scan step (16-lane rows). bound_ctrl=false + old=identity keeps
// the identity for shifted-in-from-outside lanes.
#define DPP_MAX_STEP(v, idf, ctrl)                                            \
    {                                                                         \
        union { float f; int i; } _in, _out;                                  \
        _in.f = v;                                                            \
        _out.i = __builtin_amdgcn_update_dpp(idf, _in.i, ctrl, 0xF, 0xF, false); \
        v = fmaxf(v, _out.f);                                                 \
    }

__global__ __launch_bounds__(256, 4)
void shapelet_mfma(const float* __restrict__ ts,
                   const float* __restrict__ shp,
                   const float* __restrict__ fcw,
                   const float* __restrict__ fcb,
                   float* __restrict__ out)
{
    __shared__ __align__(16) __hip_bfloat16 tsb[8][CL];          // 8 shift-copies
    __shared__ __align__(16) float          wsqT[4 * 16 * WROW]; // [w][n][j] = -wsq[w*256+16j+n]
    __shared__ __align__(16) float          red[4][L_];
    __shared__ float                        ssq[L_];

    const int tid  = threadIdx.x;
    const int b    = blockIdx.x;
    const int lane = tid & 63;
    const int w    = tid >> 6;
    const int n    = lane & 15;      // MFMA col (s within tile) / A row (l)
    const int q    = lane >> 4;      // MFMA quad

    const float* gts = ts + (size_t)b * Q_;

    // ---- epilogue params prefetched early ----
    float fw0 = 0.f, fw1 = 0.f, fb0 = 0.f, fb1 = 0.f;
    if (tid < L_) {
        fw0 = fcw[tid];
        fw1 = fcw[L_ + tid];
        fb0 = fcb[0];
        fb1 = fcb[1];
    }

    // ---- build 8 bf16 shift-copies straight from global (no LDS reads) ----
    // thread j holds ts[4j .. 4j+12) in regs, emits tsb[c][4j..4j+4) = ts[c+4j ..] for c=0..7
    {
        const int j4 = 4 * tid;
        float v[12];
        #pragma unroll
        for (int u = 0; u < 3; ++u) {
            int e = j4 + 4 * u;
            e = e > (Q_ - 4) ? (Q_ - 4) : e;          // clamped (tail threads)
            float4 x = *(const float4*)(gts + e);
            v[4*u+0] = x.x; v[4*u+1] = x.y; v[4*u+2] = x.z; v[4*u+3] = x.w;
        }
        #pragma unroll
        for (int u = 0; u < 12; ++u)
            if (j4 + u >= Q_) v[u] = 0.f;             // zero beyond series end
        #pragma unroll
        for (int c = 0; c < 8; ++c) {
            *(uint2*)&tsb[c][j4] = make_uint2(pack_bf16x2(v[c+0], v[c+1]),
                                              pack_bf16x2(v[c+2], v[c+3]));
        }
        // zero-pad x in [1024, 1048) for all copies
        if (tid < 48) {
            const int c  = tid / 6;
            const int x0 = Q_ + (tid - 6 * c) * 4;
            *(uint2*)&tsb[c][x0] = make_uint2(0u, 0u);
        }
    }

    // ---- wsq: ONE wave, 16 s per thread, from global; store transposed & negated ----
    if (tid < 64) {
        const int d = tid;
        float vv[48];
        #pragma unroll
        for (int u = 0; u < 12; ++u) {
            int e = 16 * d + 4 * u;
            e = e > (Q_ - 4) ? (Q_ - 4) : e;
            float4 x = *(const float4*)(gts + e);
            vv[4*u+0] = x.x; vv[4*u+1] = x.y; vv[4*u+2] = x.z; vv[4*u+3] = x.w;
        }
        float sq = 0.f;
        #pragma unroll
        for (int k = 0; k < K_; ++k) sq = fmaf(vv[k], vv[k], sq);
        const int wv = d >> 4, jv = d & 15;
        #pragma unroll
        for (int i = 0; i < 16; ++i) {
            const int s = 16 * d + i;
            const float o = (s < S_) ? sq * (-1.0f / K_) : -1e30f;
            wsqT[(wv * 16 + i) * WROW + jv] = o;
            sq = sq + vv[32 + i] * vv[32 + i] - vv[i] * vv[i];
        }
    }

    // ---- ssq (exact fp32) ----
    if (tid < L_) {
        const float* sp = shp + tid * K_;
        float s = 0.f;
        #pragma unroll
        for (int k = 0; k < K_; ++k) s = fmaf(sp[k], sp[k], s);
        ssq[tid] = s * (1.0f / K_);
    }

    // ---- A fragments: shapelets * 2^-4 (exact scale), built once ----
    frag_ab afrag[4];
    #pragma unroll
    for (int f = 0; f < 4; ++f) {
        const float4* sp = (const float4*)(shp + (f * 16 + n) * K_ + q * 8);
        float4 x0 = sp[0], x1 = sp[1];
        union { frag_ab v; unsigned u[4]; } uu;
        uu.u[0] = pack_bf16x2(x0.x * 0.0625f, x0.y * 0.0625f);
        uu.u[1] = pack_bf16x2(x0.z * 0.0625f, x0.w * 0.0625f);
        uu.u[2] = pack_bf16x2(x1.x * 0.0625f, x1.y * 0.0625f);
        uu.u[3] = pack_bf16x2(x1.z * 0.0625f, x1.w * 0.0625f);
        afrag[f] = uu.v;
    }
    __syncthreads();

    // ---- preload this lane's 16 (negated) wsq values: 4x ds_read_b128 ----
    float wq[16];
    {
        const float* wrow = &wsqT[(w * 16 + n) * WROW];
        #pragma unroll
        for (int t = 0; t < 4; ++t) {
            f32x4 x = *(const f32x4*)(wrow + 4 * t);
            wq[4*t+0] = x[0]; wq[4*t+1] = x[1]; wq[4*t+2] = x[2]; wq[4*t+3] = x[3];
        }
    }

    // ---- main loop: wave w -> s-tiles [w*16, w*16+16); D = (2/K)*cross - wsq ----
    const __hip_bfloat16* bp = &tsb[n & 7][8 * q + (n & 8)];
    float rm[4][4];
    #pragma unroll
    for (int f = 0; f < 4; ++f)
        #pragma unroll
        for (int r = 0; r < 4; ++r) rm[f][r] = -3e38f;

    #pragma unroll
    for (int j = 0; j < 16; ++j) {
        frag_ab bv = *(const frag_ab*)(bp + w * 256 + 16 * j);
        const float nw = wq[j];
        f32x4 cin = {nw, nw, nw, nw};
        #pragma unroll
        for (int f = 0; f < 4; ++f) {
            f32x4 d = __builtin_amdgcn_mfma_f32_16x16x32_bf16(afrag[f], bv, cin, 0, 0, 0);
            #pragma unroll
            for (int r = 0; r < 4; ++r)
                rm[f][r] = fmaxf(rm[f][r], d[r]);
        }
    }

    // ---- max across the 16 s-cols (lanes n=0..15) on the VALU pipe via DPP scan ----
    {
        union { float f; int i; } idc; idc.f = -3e38f;
        const int idf = idc.i;
        #pragma unroll
        for (int f = 0; f < 4; ++f)
            #pragma unroll
            for (int r = 0; r < 4; ++r) {
                float v = rm[f][r];
                DPP_MAX_STEP(v, idf, 0x111);   // row_shr:1
                DPP_MAX_STEP(v, idf, 0x112);   // row_shr:2
                DPP_MAX_STEP(v, idf, 0x114);   // row_shr:4
                DPP_MAX_STEP(v, idf, 0x118);   // row_shr:8
                rm[f][r] = v;                  // lane n==15 holds the row max
            }
    }
    if (n == 15) {
        #pragma unroll
        for (int f = 0; f < 4; ++f) {
            f32x4 val = {rm[f][0], rm[f][1], rm[f][2], rm[f][3]};
            *(f32x4*)&red[w][f * 16 + q * 4] = val;
        }
    }
    __syncthreads();

    // ---- final: combine waves, dist = ssq - ymax, FC, wave-64 reduce ----
    if (tid < L_) {
        const int l = tid;
        float y = fmaxf(fmaxf(red[0][l], red[1][l]), fmaxf(red[2][l], red[3][l]));
        float d = ssq[l] - y;
        float p0 = d * fw0;
        float p1 = d * fw1;
        #pragma unroll
        for (int off = 32; off > 0; off >>= 1) {
            p0 += __shfl_down(p0, off, 64);
            p1 += __shfl_down(p1, off, 64);
        }
        if (l == 0) {
            out[(size_t)b * 2 + 0] = p0 + fb0;
            out[(size_t)b * 2 + 1] = p1 + fb1;
        }
    }
}

extern "C" void kernel_launch(void* const* d_in, const int* in_sizes, int n_in,
                              void* d_out, int out_size, void* d_ws, size_t ws_size,
                              hipStream_t stream) {
    const float* ts  = (const float*)d_in[0];   // (B, Q) fp32
    const float* shp = (const float*)d_in[1];   // (L, K) fp32
    const float* fcw = (const float*)d_in[2];   // (2, L) fp32
    const float* fcb = (const float*)d_in[3];   // (2,)  fp32
    float* o = (float*)d_out;                   // (B, 2) fp32

    shapelet_mfma<<<B_, 256, 0, stream>>>(ts, shp, fcw, fcb, o);
}